// Round 1
// baseline (238.076 us; speedup 1.0000x reference)
//
#include <hip/hip_runtime.h>
#include <cmath>

#define HH 512
#define WW 512
#define TILE 32
#define HALO 5
#define IN_T (TILE + 2*HALO)   /* 42 */
#define SP_STRIDE 44
#define C1F 0.0001f
#define C2F 0.0009f

struct GaussW { float w[11]; };

__global__ __launch_bounds__(256) void ssim_tile_kernel(
    const float* __restrict__ pred, const float* __restrict__ targ,
    float* __restrict__ partial, GaussW gw)
{
    __shared__ float sp[IN_T][SP_STRIDE];
    __shared__ float st[IN_T][SP_STRIDE];
    __shared__ float hp[5][IN_T][TILE];
    __shared__ float wred[4];

    const int tid = threadIdx.x;
    const int bx = blockIdx.x, by = blockIdx.y, bz = blockIdx.z;
    const int gx0 = bx * TILE - HALO;
    const int gy0 = by * TILE - HALO;
    const size_t plane = (size_t)bz * (size_t)(HH * WW);

    // ---- stage global -> LDS with zero padding ----
    for (int i = tid; i < IN_T * IN_T; i += 256) {
        int r = i / IN_T;
        int c = i - r * IN_T;
        int gr = gy0 + r, gc = gx0 + c;
        float p = 0.f, t = 0.f;
        if (gr >= 0 && gr < HH && gc >= 0 && gc < WW) {
            size_t idx = plane + (size_t)gr * WW + gc;
            p = pred[idx];
            t = targ[idx];
        }
        sp[r][c] = p;
        st[r][c] = t;
    }
    __syncthreads();

    // ---- horizontal Gaussian pass: 5 fields over 42 rows x 32 cols ----
    for (int i = tid; i < IN_T * TILE; i += 256) {
        int r = i >> 5;       // /32
        int c = i & 31;
        float s1 = 0.f, s2 = 0.f, s11 = 0.f, s22 = 0.f, s12 = 0.f;
        #pragma unroll
        for (int k = 0; k < 11; k++) {
            float wk = gw.w[k];
            float p = sp[r][c + k];
            float t = st[r][c + k];
            s1  += wk * p;
            s2  += wk * t;
            s11 += wk * p * p;
            s22 += wk * t * t;
            s12 += wk * p * t;
        }
        hp[0][r][c] = s1;
        hp[1][r][c] = s2;
        hp[2][r][c] = s11;
        hp[3][r][c] = s22;
        hp[4][r][c] = s12;
    }
    __syncthreads();

    // ---- vertical Gaussian pass + SSIM map + local accumulation ----
    float local = 0.f;
    for (int i = tid; i < TILE * TILE; i += 256) {
        int r = i >> 5;
        int c = i & 31;
        float m1 = 0.f, m2 = 0.f, e11 = 0.f, e22 = 0.f, e12 = 0.f;
        #pragma unroll
        for (int k = 0; k < 11; k++) {
            float wk = gw.w[k];
            m1  += wk * hp[0][r + k][c];
            m2  += wk * hp[1][r + k][c];
            e11 += wk * hp[2][r + k][c];
            e22 += wk * hp[3][r + k][c];
            e12 += wk * hp[4][r + k][c];
        }
        float m1s = m1 * m1;
        float m2s = m2 * m2;
        float m12 = m1 * m2;
        float v1 = e11 - m1s;
        float v2 = e22 - m2s;
        float cv = e12 - m12;
        float num = (2.f * m12 + C1F) * (2.f * cv + C2F);
        float den = (m1s + m2s + C1F) * (v1 + v2 + C2F);
        local += num / den;
    }

    // ---- block reduction: wave shuffle then cross-wave via LDS ----
    #pragma unroll
    for (int off = 32; off > 0; off >>= 1)
        local += __shfl_down(local, off, 64);
    int lane = tid & 63, wid = tid >> 6;
    if (lane == 0) wred[wid] = local;
    __syncthreads();
    if (tid == 0) {
        int bid = (bz * gridDim.y + by) * gridDim.x + bx;
        partial[bid] = wred[0] + wred[1] + wred[2] + wred[3];
    }
}

__global__ __launch_bounds__(256) void ssim_finalize_kernel(
    const float* __restrict__ partial, int n, double inv_count,
    float* __restrict__ out)
{
    __shared__ double sm[256];
    double s = 0.0;
    for (int i = threadIdx.x; i < n; i += 256)
        s += (double)partial[i];
    sm[threadIdx.x] = s;
    __syncthreads();
    for (int off = 128; off > 0; off >>= 1) {
        if (threadIdx.x < off) sm[threadIdx.x] += sm[threadIdx.x + off];
        __syncthreads();
    }
    if (threadIdx.x == 0)
        out[0] = 1.0f - (float)(sm[0] * inv_count);
}

extern "C" void kernel_launch(void* const* d_in, const int* in_sizes, int n_in,
                              void* d_out, int out_size, void* d_ws, size_t ws_size,
                              hipStream_t stream)
{
    const float* pred = (const float*)d_in[0];
    const float* targ = (const float*)d_in[1];
    float* out = (float*)d_out;
    float* partial = (float*)d_ws;

    const int total = in_sizes[0];                 // 16*3*512*512 = 12582912
    const int nplanes = total / (HH * WW);         // 48

    // Gaussian window, computed on host in double precision.
    GaussW gw;
    double g[11], s = 0.0;
    for (int i = 0; i < 11; i++) {
        double d = (double)(i - 5);
        g[i] = exp(-d * d / 4.5);
        s += g[i];
    }
    for (int i = 0; i < 11; i++) gw.w[i] = (float)(g[i] / s);

    dim3 grid(WW / TILE, HH / TILE, nplanes);      // 16 x 16 x 48 = 12288 blocks
    ssim_tile_kernel<<<grid, 256, 0, stream>>>(pred, targ, partial, gw);

    const int nblocks = (WW / TILE) * (HH / TILE) * nplanes;
    const double inv_count = 1.0 / (double)total;
    ssim_finalize_kernel<<<1, 256, 0, stream>>>(partial, nblocks, inv_count, out);
}